// Round 2
// baseline (98.183 us; speedup 1.0000x reference)
//
#include <hip/hip_runtime.h>
#include <hip/hip_fp16.h>
#include <math.h>

// Problem constants (from reference)
#define BATCH    512
#define N_VARS   4096
#define H_DW     8194      // encode rows: [-inf, 0, pos0, neg0, ...]
#define N_OUT1   8192
#define N_OUT3   2048
#define TPB      1024

// LDS: fp16 encode table (dword idx == encode row, each __half2 = 2 batch cols)
// followed by the f32 r1 (layer-1 output) table.
#define ENC_BYTES  32800                      // 8194 dwords, padded to 8-B mult
#define R1_BYTES   (N_OUT1 * 8)               // 8192 float2 = 65536
#define SMEM_BYTES (ENC_BYTES + R1_BYTES)     // 98336 B dynamic LDS

// Fast native-transcendental variants. Accuracy budget: threshold 0.38;
// fp32 path measured absmax 0.0625; fp16 encode measured absmax 0.125.
__device__ __forceinline__ float log1mexp_fast(float x) {
    return __logf(1.0f - __expf(x));
}

__device__ __forceinline__ float2 lse2_fast2(float2 a, float2 b) {
    float2 r;
    r.x = fmaxf(a.x, b.x) + __logf(1.0f + __expf(-fabsf(a.x - b.x)));
    r.y = fmaxf(a.y, b.y) + __logf(1.0f + __expf(-fabsf(a.y - b.y)));
    return r;
}

__device__ __forceinline__ unsigned int h2u(__half2 h) {
    union { __half2 h; unsigned int u; } v; v.h = h; return v.u;
}

// {pos, neg} encode pair for two batch columns, packed as 2 dwords of __half2.
__device__ __forceinline__ uint2 enc2(float2 v) {
    uint2 r;
    r.x = h2u(__floats2half2_rn(v.x, v.y));
    r.y = h2u(__floats2half2_rn(log1mexp_fast(v.x), log1mexp_fast(v.y)));
    return r;
}

// fanin-4 product sum from the fp16 encode table (each __half2 = 2 batch cols).
// Level-1 adds in fp16 (packed), final add in f32 for accuracy.
__device__ __forceinline__ float2 gsum_h(const __half2* __restrict__ enc, int4 q) {
    __half2 v0 = enc[q.x], v1 = enc[q.y], v2 = enc[q.z], v3 = enc[q.w];
    __half2 s01 = __hadd2(v0, v1), s23 = __hadd2(v2, v3);
    float2 f01 = __half22float2(s01), f23 = __half22float2(s23);
    return make_float2(f01.x + f23.x, f01.y + f23.y);
}

// fanin-4 product sum from the f32 r1 table.
__device__ __forceinline__ float2 gsum_f(const float2* __restrict__ rb, int4 q) {
    float2 v0 = rb[q.x], v1 = rb[q.y], v2 = rb[q.z], v3 = rb[q.w];
    return make_float2(v0.x + v1.x + v2.x + v3.x, v0.y + v1.y + v2.y + v3.y);
}

// ONE kernel, no workspace. Each block owns batch-column pair bp (XCD-swizzled
// so consecutive pairs share an XCD L2 -> each 64-B x line fetched once/XCD).
// Phase A: strided float2 gather of the block's two x columns + inline encode
// (log1mexp) -> fp16 LDS table. Phase B: layer0 product(4) + layer1 lse(2),
// index chain P1->P0 inlined with rolling prefetch, results to separate LDS
// region. Phase C: layer2 product(4) + layer3 lse(2) -> out (8-B stores).
__global__ void __launch_bounds__(TPB, 4)
spn_one_kernel(const float* __restrict__ x,
               const int* __restrict__ p0,
               const int* __restrict__ p1,
               const int* __restrict__ p2,
               const int* __restrict__ p3,
               float* __restrict__ out) {
    extern __shared__ char smem[];
    const __half2* enc = (const __half2*)smem;      // dword idx == encode row
    float2* r1b = (float2*)(smem + ENC_BYTES);      // 8192 float2
    const int b  = blockIdx.x;
    const int bp = ((b & 7) << 5) | (b >> 3);       // XCD-contiguous pair id
    const int t  = threadIdx.x;

    const int2* P1 = (const int2*)p1;
    const int4* P0 = (const int4*)p0;
    const int2* P3 = (const int2*)p3;
    const int4* P2 = (const int4*)p2;

    // ---- Phase A: gather columns 2bp,2bp+1 (float2, 2-KB stride across lanes;
    //      lines shared 8-way within this XCD's L2 thanks to the swizzle). ----
    const float2* xc = (const float2*)x + bp;       // x[r][2bp] pairs
    float2 v0 = xc[(size_t)t * (BATCH / 2)];
    float2 v1 = xc[((size_t)t + 1024) * (BATCH / 2)];
    float2 v2 = xc[((size_t)t + 2048) * (BATCH / 2)];
    float2 v3 = xc[((size_t)t + 3072) * (BATCH / 2)];

    // index prefetch for outputs j=0..3 (coalesced, independent of x loads)
    int2 i0 = P1[t], i1 = P1[t + 1024], i2 = P1[t + 2048], i3 = P1[t + 3072];

    {   // inline encode -> LDS (8-B lane stride, conflict-benign)
        uint2* lu2 = (uint2*)smem;
        if (t == 0) lu2[0] = make_uint2(0xFC00FC00u, 0u);   // rows {-inf, 0}
        lu2[1 + t]        = enc2(v0);
        lu2[1 + t + 1024] = enc2(v1);
        lu2[1 + t + 2048] = enc2(v2);
        lu2[1 + t + 3072] = enc2(v3);
    }
    // dependent leaf-row loads for j=0,1 (indices arrived during encode)
    int4 a0 = P0[i0.x], b0 = P0[i0.y];
    int4 a1 = P0[i1.x], b1 = P0[i1.y];
    __syncthreads();

    // ---- Phase B: 8 outputs/thread, rolling index+row prefetch. ----
    int4 a2 = P0[i2.x], b2 = P0[i2.y];
    int4 a3 = P0[i3.x], b3 = P0[i3.y];
    int2 i4 = P1[t + 4096], i5 = P1[t + 5120];
    int2 i6 = P1[t + 6144], i7 = P1[t + 7168];

    r1b[t]        = lse2_fast2(gsum_h(enc, a0), gsum_h(enc, b0));
    r1b[t + 1024] = lse2_fast2(gsum_h(enc, a1), gsum_h(enc, b1));

    int4 a4 = P0[i4.x], b4 = P0[i4.y];
    int4 a5 = P0[i5.x], b5 = P0[i5.y];

    r1b[t + 2048] = lse2_fast2(gsum_h(enc, a2), gsum_h(enc, b2));
    r1b[t + 3072] = lse2_fast2(gsum_h(enc, a3), gsum_h(enc, b3));

    int4 a6 = P0[i6.x], b6 = P0[i6.y];
    int4 a7 = P0[i7.x], b7 = P0[i7.y];
    // phase-C index prefetch
    int2 c0i = P3[t], c1i = P3[t + 1024];

    r1b[t + 4096] = lse2_fast2(gsum_h(enc, a4), gsum_h(enc, b4));
    r1b[t + 5120] = lse2_fast2(gsum_h(enc, a5), gsum_h(enc, b5));

    // phase-C row prefetch (hides L2 latency behind the last chunk + barrier)
    int4 ca = P2[c0i.x], cb = P2[c0i.y];
    int4 cc = P2[c1i.x], cd = P2[c1i.y];

    r1b[t + 6144] = lse2_fast2(gsum_h(enc, a6), gsum_h(enc, b6));
    r1b[t + 7168] = lse2_fast2(gsum_h(enc, a7), gsum_h(enc, b7));
    __syncthreads();

    // ---- Phase C: product(4)+lse(2) -> out[o][2bp..2bp+1] (8-B store) ----
    {
        float2 ga = gsum_f(r1b, ca), gb = gsum_f(r1b, cb);
        ((float2*)(out + (size_t)t * BATCH))[bp] = lse2_fast2(ga, gb);
        float2 ga1 = gsum_f(r1b, cc), gb1 = gsum_f(r1b, cd);
        ((float2*)(out + (size_t)(t + 1024) * BATCH))[bp] = lse2_fast2(ga1, gb1);
    }
}

extern "C" void kernel_launch(void* const* d_in, const int* in_sizes, int n_in,
                              void* d_out, int out_size, void* d_ws, size_t ws_size,
                              hipStream_t stream) {
    const float* x     = (const float*)d_in[0];
    const int*   ptrs0 = (const int*)d_in[1];
    const int*   ptrs1 = (const int*)d_in[3];
    const int*   ptrs2 = (const int*)d_in[5];
    const int*   ptrs3 = (const int*)d_in[7];
    float* out = (float*)d_out;
    (void)d_ws; (void)ws_size;   // no workspace needed anymore

    // Allow >64 KB dynamic LDS (gfx950: 160 KB/WG). Unconditional each call.
    hipFuncSetAttribute((const void*)spn_one_kernel,
                        hipFuncAttributeMaxDynamicSharedMemorySize, SMEM_BYTES);

    spn_one_kernel<<<BATCH / 2, TPB, SMEM_BYTES, stream>>>(
        x, ptrs0, ptrs1, ptrs2, ptrs3, out);
}

// Round 3
// 90.068 us; speedup vs baseline: 1.0901x; 1.0901x over previous
//
#include <hip/hip_runtime.h>
#include <hip/hip_fp16.h>
#include <math.h>

// Problem constants (from reference)
#define BATCH    512
#define N_VARS   4096
#define H_ROWS   (2 * N_VARS + 2)   // 8194 encode rows
#define N_OUT1   8192
#define N_OUT3   2048
#define TPB      1024

// Encode-slab layout: per batch-PAIR, uint2[S_U2]; u2[0] = header rows {-inf, 0},
// u2[1+v] = rows {pos_v, neg_v}. As a dword array, dword index == encode row index.
#define S_U2       4100
#define ENC_BYTES  (S_U2 * 8)                 // 32800 B per slab
#define ENC_WS_BYTES ((size_t)(BATCH / 2) * ENC_BYTES)   // 256 slabs
#define R1_BYTES   (N_OUT1 * 8)               // 8192 float2 = 65536
#define SMEM_BYTES (ENC_BYTES + R1_BYTES)     // 98336 B dynamic LDS

// Fast native-transcendental variants. Accuracy budget: threshold 0.38;
// fp32 path measured absmax 0.0625; fp16 encode measured absmax 0.125.
__device__ __forceinline__ float log1mexp_fast(float x) {
    return __logf(1.0f - __expf(x));
}

__device__ __forceinline__ float2 lse2_fast2(float2 a, float2 b) {
    float2 r;
    r.x = fmaxf(a.x, b.x) + __logf(1.0f + __expf(-fabsf(a.x - b.x)));
    r.y = fmaxf(a.y, b.y) + __logf(1.0f + __expf(-fabsf(a.y - b.y)));
    return r;
}

__device__ __forceinline__ unsigned int h2u(__half2 h) {
    union { __half2 h; unsigned int u; } v; v.h = h; return v.u;
}

// fanin-4 product sum from the fp16 encode table (each __half2 = 2 batch cols).
// Level-1 adds in fp16 (packed), final add in f32 for accuracy.
__device__ __forceinline__ float2 gsum_h(const __half2* __restrict__ enc, int4 q) {
    __half2 v0 = enc[q.x], v1 = enc[q.y], v2 = enc[q.z], v3 = enc[q.w];
    __half2 s01 = __hadd2(v0, v1), s23 = __hadd2(v2, v3);
    float2 f01 = __half22float2(s01), f23 = __half22float2(s23);
    return make_float2(f01.x + f23.x, f01.y + f23.y);
}

// fanin-4 product sum from the f32 r1 table.
__device__ __forceinline__ float2 gsum_f(const float2* __restrict__ rb, int4 q) {
    float2 v0 = rb[q.x], v1 = rb[q.y], v2 = rb[q.z], v3 = rb[q.w];
    return make_float2(v0.x + v1.x + v2.x + v3.x, v0.y + v1.y + v2.y + v3.y);
}

// ---- Prep kernel: fused {transpose + encode(log1mexp) + fp16 pack} AND
// gather-table build in ONE dispatch. (Verified structure from R1.)
#define TDIM    32
#define NTRANS  ((BATCH / TDIM) * (N_VARS / TDIM))   // 16 * 128 = 2048
#define NTAB    ((N_OUT1 + N_OUT3) / 256)            // 40
__global__ void prep_kernel(const float* __restrict__ x,
                            uint2* __restrict__ encE,
                            const int* __restrict__ p0,
                            const int* __restrict__ p1,
                            const int* __restrict__ p2,
                            const int* __restrict__ p3,
                            int4* __restrict__ tabB,
                            int4* __restrict__ tabC) {
    __shared__ float tile[TDIM][TDIM + 1];
    int blk = blockIdx.x;
    int tx = threadIdx.x, ty = threadIdx.y;
    if (blk < NTRANS) {
        int cb = (blk % (BATCH / TDIM)) * TDIM;   // batch-col base (mult of 32)
        int rb = (blk / (BATCH / TDIM)) * TDIM;   // var base
#pragma unroll
        for (int j = 0; j < TDIM; j += 8)
            tile[ty + j][tx] = x[(size_t)(rb + ty + j) * BATCH + cb + tx];
        __syncthreads();
        int tid = ty * TDIM + tx;   // 0..255
#pragma unroll
        for (int k = 0; k < 2; ++k) {
            int q = tid + k * 256;          // 512 items = 16 pairs x 32 vars
            int vl = q & 31;                // var-local (fastest -> coalesced)
            int pl = q >> 5;                // pair-local 0..15
            float a = tile[vl][2 * pl];
            float b = tile[vl][2 * pl + 1];
            uint2 val;
            val.x = h2u(__floats2half2_rn(a, b));
            val.y = h2u(__floats2half2_rn(log1mexp_fast(a), log1mexp_fast(b)));
            encE[(size_t)(cb / 2 + pl) * S_U2 + 1 + rb + vl] = val;
        }
        if (rb == 0 && tid < 16)   // header rows {-inf,-inf},{0,0} once per pair
            encE[(size_t)(cb / 2 + tid) * S_U2] = make_uint2(0xFC00FC00u, 0u);
    } else {
        int o = (blk - NTRANS) * 256 + ty * TDIM + tx;
        if (o < N_OUT1) {
            int2 pp = ((const int2*)p1)[o];
            tabB[2 * o]     = ((const int4*)p0)[pp.x];
            tabB[2 * o + 1] = ((const int4*)p0)[pp.y];
        } else {
            int oc = o - N_OUT1;
            int2 pp = ((const int2*)p3)[oc];
            tabC[2 * oc]     = ((const int4*)p2)[pp.x];
            tabC[2 * oc + 1] = ((const int4*)p2)[pp.y];
        }
    }
}

// TWO adjacent batch columns per workgroup. Changes vs R1:
//  (1) bp is XCD-swizzled so each XCD owns 32 CONTIGUOUS pairs -> each 64-B
//      out line (8 pairs) is completed inside ONE XCD's L2 (kills ~8x HBM
//      write amplification from cross-XCD partial-line dirt).
//  (2) Phase-A slab staged via global_load_lds width=16 (linear LDS dest,
//      contiguous global src — the exact DMA-friendly pattern), no VGPR trip.
__global__ void __launch_bounds__(TPB, 4)
fused_spn_kernel(const uint2* __restrict__ encE,
                 const int4* __restrict__ tabB,
                 const int4* __restrict__ tabC,
                 float* __restrict__ out) {
    extern __shared__ char smem[];
    const __half2* enc = (const __half2*)smem;         // dword idx == encode row
    float2* r1b = (float2*)(smem + ENC_BYTES);         // 8192 float2
    const int b  = blockIdx.x;
    const int bp = ((b & 7) << 5) | (b >> 3);          // XCD-contiguous pair id
    const int t  = threadIdx.x;

    // ---- Phase A: slab -> LDS via direct DMA (2 full rounds + 32-B tail). ----
    {
        const char* gsrc = (const char*)(encE + (size_t)bp * S_U2);
        __builtin_amdgcn_global_load_lds(
            (const __attribute__((address_space(1))) void*)(gsrc + (size_t)t * 16),
            (__attribute__((address_space(3))) void*)(smem + (size_t)t * 16),
            16, 0, 0);
        __builtin_amdgcn_global_load_lds(
            (const __attribute__((address_space(1))) void*)(gsrc + 16384 + (size_t)t * 16),
            (__attribute__((address_space(3))) void*)(smem + 16384 + (size_t)t * 16),
            16, 0, 0);
        if (t < 2)
            __builtin_amdgcn_global_load_lds(
                (const __attribute__((address_space(1))) void*)(gsrc + 32768 + (size_t)t * 16),
                (__attribute__((address_space(3))) void*)(smem + 32768 + (size_t)t * 16),
                16, 0, 0);
    }
    // tab chunk-0 prefetch (independent of the LDS staging)
    int4 a0A = tabB[2 * t],          b0A = tabB[2 * t + 1];
    int4 a1A = tabB[2 * (t + 1024)], b1A = tabB[2 * (t + 1024) + 1];
    __syncthreads();   // drains vmcnt -> slab resident

    // ---- Phase B: 8 outputs/thread, rolling tab prefetch, r1 stored to a
    //      separate LDS region as produced. ----
    int4 a0B = tabB[2 * (t + 2048)], b0B = tabB[2 * (t + 2048) + 1];
    int4 a1B = tabB[2 * (t + 3072)], b1B = tabB[2 * (t + 3072) + 1];

    r1b[t]        = lse2_fast2(gsum_h(enc, a0A), gsum_h(enc, b0A));
    r1b[t + 1024] = lse2_fast2(gsum_h(enc, a1A), gsum_h(enc, b1A));

    a0A = tabB[2 * (t + 4096)]; b0A = tabB[2 * (t + 4096) + 1];
    a1A = tabB[2 * (t + 5120)]; b1A = tabB[2 * (t + 5120) + 1];

    r1b[t + 2048] = lse2_fast2(gsum_h(enc, a0B), gsum_h(enc, b0B));
    r1b[t + 3072] = lse2_fast2(gsum_h(enc, a1B), gsum_h(enc, b1B));

    a0B = tabB[2 * (t + 6144)]; b0B = tabB[2 * (t + 6144) + 1];
    a1B = tabB[2 * (t + 7168)]; b1B = tabB[2 * (t + 7168) + 1];
    // Phase-C tab prefetch (hides L2 latency behind chunk 3 + barrier)
    int4 ca0 = tabC[2 * t],          cb0 = tabC[2 * t + 1];
    int4 ca1 = tabC[2 * (t + 1024)], cb1 = tabC[2 * (t + 1024) + 1];

    r1b[t + 4096] = lse2_fast2(gsum_h(enc, a0A), gsum_h(enc, b0A));
    r1b[t + 5120] = lse2_fast2(gsum_h(enc, a1A), gsum_h(enc, b1A));

    r1b[t + 6144] = lse2_fast2(gsum_h(enc, a0B), gsum_h(enc, b0B));
    r1b[t + 7168] = lse2_fast2(gsum_h(enc, a1B), gsum_h(enc, b1B));
    __syncthreads();

    // ---- Phase C: product(4)+lse(2) -> out[o][2bp..2bp+1] (8-B store) ----
    {
        float2 ga = gsum_f(r1b, ca0), gb = gsum_f(r1b, cb0);
        ((float2*)(out + (size_t)t * BATCH))[bp] = lse2_fast2(ga, gb);
        float2 ga1 = gsum_f(r1b, ca1), gb1 = gsum_f(r1b, cb1);
        ((float2*)(out + (size_t)(t + 1024) * BATCH))[bp] = lse2_fast2(ga1, gb1);
    }
}

extern "C" void kernel_launch(void* const* d_in, const int* in_sizes, int n_in,
                              void* d_out, int out_size, void* d_ws, size_t ws_size,
                              hipStream_t stream) {
    const float* x     = (const float*)d_in[0];
    const int*   ptrs0 = (const int*)d_in[1];
    const int*   ptrs1 = (const int*)d_in[3];
    const int*   ptrs2 = (const int*)d_in[5];
    const int*   ptrs3 = (const int*)d_in[7];
    float* out = (float*)d_out;

    uint2* encE = (uint2*)d_ws;                              // 8.4 MB
    int4*  tabB = (int4*)((char*)d_ws + ENC_WS_BYTES);       // 256 KB
    int4*  tabC = tabB + 2 * N_OUT1;                         // 64 KB

    // Allow >64 KB dynamic LDS (gfx950: 160 KB/WG). Unconditional each call.
    hipFuncSetAttribute((const void*)fused_spn_kernel,
                        hipFuncAttributeMaxDynamicSharedMemorySize, SMEM_BYTES);

    prep_kernel<<<NTRANS + NTAB, dim3(32, 8), 0, stream>>>(
        x, encE, ptrs0, ptrs1, ptrs2, ptrs3, tabB, tabC);

    fused_spn_kernel<<<BATCH / 2, TPB, SMEM_BYTES, stream>>>(encE, tabB, tabC, out);
}

// Round 4
// 88.788 us; speedup vs baseline: 1.1058x; 1.0144x over previous
//
#include <hip/hip_runtime.h>
#include <hip/hip_fp16.h>
#include <math.h>

// Problem constants (from reference)
#define BATCH    512
#define N_VARS   4096
#define N_OUT1   8192
#define N_OUT3   2048
#define TPB      1024

// Workspace: per batch-PAIR, pos-only fp16 slab: dword v = half2{pos[col a],
// pos[col b]} for var v. neg is recomputed in the fused kernel (log1mexp).
#define S_DW        4096                      // dwords per pair slab (16 KB)
#define ENC_WS_BYTES ((size_t)(BATCH / 2) * S_DW * 4)    // 4 MB
// LDS: full encode table (8194 dwords: [-inf,0,pos0,neg0,...] as half2 pairs)
// then the f32 r1 region.
#define ENC_BYTES  32800                      // 8194 dwords, padded
#define R1_BYTES   (N_OUT1 * 8)               // 8192 float2 = 65536
#define SMEM_BYTES (ENC_BYTES + R1_BYTES)     // 98336 B dynamic LDS

// Fast native-transcendental variants. Accuracy budget: threshold 0.38;
// measured absmax so far 0.125.
__device__ __forceinline__ float log1mexp_fast(float x) {
    return __logf(1.0f - __expf(x));
}

__device__ __forceinline__ float2 lse2_fast2(float2 a, float2 b) {
    float2 r;
    r.x = fmaxf(a.x, b.x) + __logf(1.0f + __expf(-fabsf(a.x - b.x)));
    r.y = fmaxf(a.y, b.y) + __logf(1.0f + __expf(-fabsf(a.y - b.y)));
    return r;
}

__device__ __forceinline__ unsigned int h2u(__half2 h) {
    union { __half2 h; unsigned int u; } v; v.h = h; return v.u;
}
__device__ __forceinline__ __half2 u2h(unsigned int u) {
    union { unsigned int u; __half2 h; } v; v.u = u; return v.h;
}

// {pos, neg} LDS entry from a packed pos dword (2 batch cols).
__device__ __forceinline__ uint2 encp(unsigned int p) {
    float2 f = __half22float2(u2h(p));
    uint2 r;
    r.x = p;
    r.y = h2u(__floats2half2_rn(log1mexp_fast(f.x), log1mexp_fast(f.y)));
    return r;
}

// fanin-4 product sum from the fp16 encode table (each __half2 = 2 batch cols).
// Level-1 adds in fp16 (packed), final add in f32 for accuracy.
__device__ __forceinline__ float2 gsum_h(const __half2* __restrict__ enc, int4 q) {
    __half2 v0 = enc[q.x], v1 = enc[q.y], v2 = enc[q.z], v3 = enc[q.w];
    __half2 s01 = __hadd2(v0, v1), s23 = __hadd2(v2, v3);
    float2 f01 = __half22float2(s01), f23 = __half22float2(s23);
    return make_float2(f01.x + f23.x, f01.y + f23.y);
}

// fanin-4 product sum from the f32 r1 table.
__device__ __forceinline__ float2 gsum_f(const float2* __restrict__ rb, int4 q) {
    float2 v0 = rb[q.x], v1 = rb[q.y], v2 = rb[q.z], v3 = rb[q.w];
    return make_float2(v0.x + v1.x + v2.x + v3.x, v0.y + v1.y + v2.y + v3.y);
}

// ---- Prep kernel: {transpose + fp16 pos pack} AND gather-table build in ONE
// dispatch. neg is NOT stored (recomputed in fused) — halves enc traffic.
#define TDIM    32
#define NTRANS  ((BATCH / TDIM) * (N_VARS / TDIM))   // 16 * 128 = 2048
#define NTAB    ((N_OUT1 + N_OUT3) / 256)            // 40
__global__ void prep_kernel(const float* __restrict__ x,
                            unsigned int* __restrict__ encP,
                            const int* __restrict__ p0,
                            const int* __restrict__ p1,
                            const int* __restrict__ p2,
                            const int* __restrict__ p3,
                            int4* __restrict__ tabB,
                            int4* __restrict__ tabC) {
    __shared__ float tile[TDIM][TDIM + 1];
    int blk = blockIdx.x;
    int tx = threadIdx.x, ty = threadIdx.y;
    if (blk < NTRANS) {
        int cb = (blk % (BATCH / TDIM)) * TDIM;   // batch-col base (mult of 32)
        int rb = (blk / (BATCH / TDIM)) * TDIM;   // var base
#pragma unroll
        for (int j = 0; j < TDIM; j += 8)
            tile[ty + j][tx] = x[(size_t)(rb + ty + j) * BATCH + cb + tx];
        __syncthreads();
        int tid = ty * TDIM + tx;   // 0..255
#pragma unroll
        for (int k = 0; k < 2; ++k) {
            int q = tid + k * 256;          // 512 items = 16 pairs x 32 vars
            int vl = q & 31;                // var-local (fastest -> coalesced)
            int pl = q >> 5;                // pair-local 0..15
            float a = tile[vl][2 * pl];
            float b = tile[vl][2 * pl + 1];
            encP[(size_t)(cb / 2 + pl) * S_DW + rb + vl] =
                h2u(__floats2half2_rn(a, b));
        }
    } else {
        int o = (blk - NTRANS) * 256 + ty * TDIM + tx;
        if (o < N_OUT1) {
            int2 pp = ((const int2*)p1)[o];
            tabB[2 * o]     = ((const int4*)p0)[pp.x];
            tabB[2 * o + 1] = ((const int4*)p0)[pp.y];
        } else {
            int oc = o - N_OUT1;
            int2 pp = ((const int2*)p3)[oc];
            tabC[2 * oc]     = ((const int4*)p2)[pp.x];
            tabC[2 * oc + 1] = ((const int4*)p2)[pp.y];
        }
    }
}

// TWO adjacent batch columns per workgroup (R1-verified structure; R3's null
// changes reverted). Phase A: 4 coalesced dword loads of the pos slab, neg
// recomputed inline, uint2 LDS writes at 8-B lane stride (conflict-benign).
__global__ void __launch_bounds__(TPB, 4)
fused_spn_kernel(const unsigned int* __restrict__ encP,
                 const int4* __restrict__ tabB,
                 const int4* __restrict__ tabC,
                 float* __restrict__ out) {
    extern __shared__ char smem[];
    const __half2* enc = (const __half2*)smem;         // dword idx == encode row
    float2* r1b = (float2*)(smem + ENC_BYTES);         // 8192 float2
    const int bp = blockIdx.x;                          // columns 2*bp, 2*bp+1
    const int t  = threadIdx.x;

    // ---- Phase A: pos slab -> regs (coalesced), encode -> LDS ----
    const unsigned int* src = encP + (size_t)bp * S_DW;
    unsigned int q0 = src[t], q1 = src[t + 1024];
    unsigned int q2 = src[t + 2048], q3 = src[t + 3072];
    // tab chunk-0 prefetch (independent of slab loads)
    int4 a0A = tabB[2 * t],          b0A = tabB[2 * t + 1];
    int4 a1A = tabB[2 * (t + 1024)], b1A = tabB[2 * (t + 1024) + 1];
    {
        uint2* lu2 = (uint2*)smem;
        if (t == 0) lu2[0] = make_uint2(0xFC00FC00u, 0u);   // rows {-inf, 0}
        lu2[1 + t]        = encp(q0);
        lu2[1 + t + 1024] = encp(q1);
        lu2[1 + t + 2048] = encp(q2);
        lu2[1 + t + 3072] = encp(q3);
    }
    __syncthreads();

    // ---- Phase B: 8 outputs/thread, rolling tab prefetch, r1 stored to a
    //      separate LDS region as produced. ----
    int4 a0B = tabB[2 * (t + 2048)], b0B = tabB[2 * (t + 2048) + 1];
    int4 a1B = tabB[2 * (t + 3072)], b1B = tabB[2 * (t + 3072) + 1];

    r1b[t]        = lse2_fast2(gsum_h(enc, a0A), gsum_h(enc, b0A));
    r1b[t + 1024] = lse2_fast2(gsum_h(enc, a1A), gsum_h(enc, b1A));

    a0A = tabB[2 * (t + 4096)]; b0A = tabB[2 * (t + 4096) + 1];
    a1A = tabB[2 * (t + 5120)]; b1A = tabB[2 * (t + 5120) + 1];

    r1b[t + 2048] = lse2_fast2(gsum_h(enc, a0B), gsum_h(enc, b0B));
    r1b[t + 3072] = lse2_fast2(gsum_h(enc, a1B), gsum_h(enc, b1B));

    a0B = tabB[2 * (t + 6144)]; b0B = tabB[2 * (t + 6144) + 1];
    a1B = tabB[2 * (t + 7168)]; b1B = tabB[2 * (t + 7168) + 1];
    // Phase-C tab prefetch (hides L2 latency behind the last chunks + barrier)
    int4 ca0 = tabC[2 * t],          cb0 = tabC[2 * t + 1];
    int4 ca1 = tabC[2 * (t + 1024)], cb1 = tabC[2 * (t + 1024) + 1];

    r1b[t + 4096] = lse2_fast2(gsum_h(enc, a0A), gsum_h(enc, b0A));
    r1b[t + 5120] = lse2_fast2(gsum_h(enc, a1A), gsum_h(enc, b1A));

    r1b[t + 6144] = lse2_fast2(gsum_h(enc, a0B), gsum_h(enc, b0B));
    r1b[t + 7168] = lse2_fast2(gsum_h(enc, a1B), gsum_h(enc, b1B));
    __syncthreads();

    // ---- Phase C: product(4)+lse(2) -> out[o][2bp..2bp+1] (8-B store) ----
    {
        float2 ga = gsum_f(r1b, ca0), gb = gsum_f(r1b, cb0);
        ((float2*)(out + (size_t)t * BATCH))[bp] = lse2_fast2(ga, gb);
        float2 ga1 = gsum_f(r1b, ca1), gb1 = gsum_f(r1b, cb1);
        ((float2*)(out + (size_t)(t + 1024) * BATCH))[bp] = lse2_fast2(ga1, gb1);
    }
}

extern "C" void kernel_launch(void* const* d_in, const int* in_sizes, int n_in,
                              void* d_out, int out_size, void* d_ws, size_t ws_size,
                              hipStream_t stream) {
    const float* x     = (const float*)d_in[0];
    const int*   ptrs0 = (const int*)d_in[1];
    const int*   ptrs1 = (const int*)d_in[3];
    const int*   ptrs2 = (const int*)d_in[5];
    const int*   ptrs3 = (const int*)d_in[7];
    float* out = (float*)d_out;

    unsigned int* encP = (unsigned int*)d_ws;            // 4 MB
    int4* tabB = (int4*)((char*)d_ws + ENC_WS_BYTES);    // 256 KB
    int4* tabC = tabB + 2 * N_OUT1;                      // 64 KB

    // Allow >64 KB dynamic LDS (gfx950: 160 KB/WG). Unconditional each call.
    hipFuncSetAttribute((const void*)fused_spn_kernel,
                        hipFuncAttributeMaxDynamicSharedMemorySize, SMEM_BYTES);

    prep_kernel<<<NTRANS + NTAB, dim3(32, 8), 0, stream>>>(
        x, encP, ptrs0, ptrs1, ptrs2, ptrs3, tabB, tabC);

    fused_spn_kernel<<<BATCH / 2, TPB, SMEM_BYTES, stream>>>(encP, tabB, tabC, out);
}